// Round 10
// baseline (186.522 us; speedup 1.0000x reference)
//
#include <hip/hip_runtime.h>

#define Bb 16
#define Lq 2048
#define Dd 64
#define QT 32          // q-rows per block
#define NT 512         // 8 waves: (qt = w>>2, ks = w&3)

typedef _Float16 f16x2 __attribute__((ext_vector_type(2)));
typedef _Float16 f16x8 __attribute__((ext_vector_type(8)));
typedef __attribute__((ext_vector_type(4))) float f32x4;
typedef __attribute__((ext_vector_type(2))) float f32x2;
typedef __attribute__((ext_vector_type(4))) unsigned int u32x4;
typedef __attribute__((ext_vector_type(2))) unsigned int u32x2;
typedef __attribute__((ext_vector_type(4))) int i32x4;
typedef unsigned long long u64;
typedef __attribute__((ext_vector_type(2))) unsigned long long u64x2;

union H8 { f16x8 v8; f16x2 h2[4]; unsigned int u[4]; u32x4 u4; };
union H1 { f16x2 h; unsigned int u; };

__device__ __forceinline__ f16x2 pkrtz(float a, float b) {
  return __builtin_bit_cast(f16x2, __builtin_amdgcn_cvt_pkrtz(a, b));
}
__device__ __forceinline__ f32x4 MF16(f16x8 a, f16x8 b, f32x4 c) {
  return __builtin_amdgcn_mfma_f32_16x16x32_f16(a, b, c, 0, 0, 0);
}
__device__ __forceinline__ f32x4 MFu(u32x4 a, const H8& b, f32x4 c) {
  return MF16(__builtin_bit_cast(f16x8, a), b.v8, c);
}
// async global->LDS DMA, 16B/lane; dst wave-uniform base (+lane*16 by HW)
__device__ __forceinline__ void gl_lds16(const void* g, void* l) {
  __builtin_amdgcn_global_load_lds(
      (const __attribute__((address_space(1))) void*)g,
      (__attribute__((address_space(3))) void*)l, 16, 0, 0);
}

// ---- prep: K -> interleaved h/l 64KB windows, slot-swizzled (linear DMA +
//      swizzled ds_read = both-sides rule); V -> B-frag order; mask -> bitplanes
__global__ __launch_bounds__(256)
void sdpa_prep(const float* __restrict__ kg, const float* __restrict__ vg,
               const i32x4* __restrict__ mg4,
               u32x4* __restrict__ Kw4, u32x4* __restrict__ Vq,
               u64* __restrict__ mb)
{
  const int t = threadIdx.x, blk = blockIdx.x;
  if (blk < 1024) {                        // K: 32 rows/block, 8 octets/row
    const int row = blk * 32 + (t >> 3);
    const int oct = t & 7;
    const int b = row >> 11, r = row & 2047;
    const int win = r >> 8, rw = r & 255;
    const float* kp = kg + (size_t)row * Dd + oct * 8;
    f32x4 a = *(const f32x4*)kp;
    f32x4 c = *(const f32x4*)(kp + 4);
    H1 h0, h1, h2, h3, l0, l1, l2, l3;
    h0.h = pkrtz(a.x, a.y); l0.h = pkrtz(a.x - (float)h0.h.x, a.y - (float)h0.h.y);
    h1.h = pkrtz(a.z, a.w); l1.h = pkrtz(a.z - (float)h1.h.x, a.w - (float)h1.h.y);
    h2.h = pkrtz(c.x, c.y); l2.h = pkrtz(c.x - (float)h2.h.x, c.y - (float)h2.h.y);
    h3.h = pkrtz(c.z, c.w); l3.h = pkrtz(c.z - (float)h3.h.x, c.w - (float)h3.h.y);
    u32x4 hh = {h0.u, h1.u, h2.u, h3.u};
    u32x4 ll = {l0.u, l1.u, l2.u, l3.u};
    const int sl = oct ^ (rw & 7);
    const size_t base = ((size_t)((b * 8 + win) * 256 + rw)) * 16;
    Kw4[base + sl] = hh;
    Kw4[base + 8 + sl] = ll;
  } else if (blk < 2048) {                 // V: one B-frag u32x4/thread
    const int v_ = (blk - 1024) * 256 + t;
    const int ln = v_ & 15, nt = (v_ >> 4) & 3, u = (v_ >> 6) & 3;
    const int g = (v_ >> 8) & 7, w = (v_ >> 11) & 7, b = v_ >> 14;
    const int R = w * 256 + g * 32 + u * 4;
    const float* vp = vg + ((size_t)b * Lq + R) * Dd + nt * 16 + ln;
    H1 p0, p1, p2, p3;
    p0.h = pkrtz(vp[0 * Dd],  vp[1 * Dd]);
    p1.h = pkrtz(vp[2 * Dd],  vp[3 * Dd]);
    p2.h = pkrtz(vp[16 * Dd], vp[17 * Dd]);
    p3.h = pkrtz(vp[18 * Dd], vp[19 * Dd]);
    u32x4 o = {p0.u, p1.u, p2.u, p3.u};
    Vq[v_] = o;
  } else {                                 // mask: window=256 cols -> 4 u64 ballots
    const int l  = t & 63;
    const int wg = ((blk - 2048) << 2) | (t >> 6);
    i32x4 cur = __builtin_nontemporal_load(&mg4[((size_t)wg * 32) * 64 + l]);
#pragma unroll 1
    for (int it = 0; it < 32; ++it) {
      i32x4 nxt = {0, 0, 0, 0};
      if (it < 31) nxt = __builtin_nontemporal_load(&mg4[((size_t)wg * 32 + it + 1) * 64 + l]);
      u64 b0 = __ballot(cur.x != 0);
      u64 b1 = __ballot(cur.y != 0);
      u64 b2 = __ballot(cur.z != 0);
      u64 b3 = __ballot(cur.w != 0);
      if (l == 0) {
        u64* o = mb + ((size_t)wg * 32 + it) * 4;
        u64x2 w0 = {b0, b1}, w1 = {b2, b3};
        *(u64x2*)o = w0;
        *(u64x2*)(o + 2) = w1;
      }
      cur = nxt;
    }
  }
}

// ---------------------------- main kernel ----------------------------
__global__ __launch_bounds__(NT, 2)
void sdpa_main(const float* __restrict__ qg, const char* __restrict__ Kw,
               const u32x4* __restrict__ Vqp, const u64* __restrict__ mbp,
               float* __restrict__ outO, float* __restrict__ outA)
{
  __shared__ char kbuf[2][65536];                   // K-window double buffer
  __shared__ unsigned int Qh[QT][36], Ql[QT][36];   // 9.2 KB
  __shared__ float red[QT][4];
  __shared__ float dinv_s[QT];

  const int tid = threadIdx.x;
  const int l   = tid & 63;
  const int ln  = l & 15;
  const int u   = l >> 4;
  const int w   = tid >> 6;        // 0..7
  const int qt  = w >> 2;          // q-tile 0/1
  const int ks  = w & 3;           // k-quarter of window (64 rows)
  const int bid = (int)(blockIdx.x % 8) * 128 + (int)(blockIdx.x / 8); // XCD swz
  const int b   = bid >> 6;
  const int q0  = (bid & 63) * QT;

  // Phase 0: Q (32 rows) -> f16 h/l split planes in LDS
  {
    int r = tid >> 4, i4 = tid & 15;
    f32x4 qv = *(const f32x4*)(qg + (size_t)(b * Lq + q0 + r) * Dd + 4 * i4);
    H1 ha, hb, la, lb;
    ha.h = pkrtz(qv.x, qv.y); la.h = pkrtz(qv.x - (float)ha.h.x, qv.y - (float)ha.h.y);
    hb.h = pkrtz(qv.z, qv.w); lb.h = pkrtz(qv.z - (float)hb.h.x, qv.w - (float)hb.h.y);
    Qh[r][2 * i4] = ha.u; Qh[r][2 * i4 + 1] = hb.u;
    Ql[r][2 * i4] = la.u; Ql[r][2 * i4 + 1] = lb.u;
  }

  const char* kwb = Kw + (size_t)b * 8 * 65536;
  auto STAGE = [&](int buf_, int win_) {
#pragma unroll
    for (int i = 0; i < 8; ++i)
      gl_lds16(kwb + (size_t)win_ * 65536 + i * 8192 + w * 1024 + l * 16,
               &kbuf[buf_][i * 8192 + w * 1024]);
  };
  STAGE(0, 0);
  __syncthreads();   // Q planes + window-0 DMA drained

  H8 Bh0, Bh1, Bl0, Bl1;
  Bh0.u4 = *(const u32x4*)&Qh[16 * qt + ln][4 * u];
  Bh1.u4 = *(const u32x4*)&Qh[16 * qt + ln][16 + 4 * u];
  Bl0.u4 = *(const u32x4*)&Ql[16 * qt + ln][4 * u];
  Bl1.u4 = *(const u32x4*)&Ql[16 * qt + ln][16 + 4 * u];

  const u64* mrow = mbp + (size_t)(b * Lq + q0 + 16 * qt + ln) * 32;
  unsigned int su[8][4][2];                 // S f16-pairs, whole k-range of wave
  float rs = 0.f;
  const int key   = ln & 7;
  const int rbase = ks * 64;
  const int shb   = u + ((ks & 1) << 4);
  const bool lowh = (ks < 2);

  // ---- loop1: QK^T only (K DMA double-buffered), S stays in registers ----
#pragma unroll
  for (int win = 0; win < 8; ++win) {
    const int cur = win & 1;
    if (win < 7) STAGE(cur ^ 1, win + 1);

    u32x4 MA = *(const u32x4*)(mrow + win * 4);
    u32x4 MC = *(const u32x4*)(mrow + win * 4 + 2);
    unsigned mw0 = lowh ? MA.x : MA.y;
    unsigned mw1 = lowh ? MA.z : MA.w;
    unsigned mw2 = lowh ? MC.x : MC.y;
    unsigned mw3 = lowh ? MC.z : MC.w;

    const char* kb_ = &kbuf[cur][0];
#pragma unroll
    for (int t = 0; t < 4; ++t) {
      const int rw = rbase + 16 * t + ln;
      const char* rp = kb_ + rw * 256;
      u32x4 h0  = *(const u32x4*)(rp + ((u ^ key) << 4));
      u32x4 h1  = *(const u32x4*)(rp + (((4 + u) ^ key) << 4));
      u32x4 l0_ = *(const u32x4*)(rp + ((8 | (u ^ key)) << 4));
      u32x4 l1_ = *(const u32x4*)(rp + ((8 | ((4 + u) ^ key)) << 4));
      f32x4 acc = {0.f, 0.f, 0.f, 0.f};
      acc = MFu(h0, Bh0, acc);
      acc = MFu(h0, Bl0, acc);
      acc = MFu(l0_, Bh0, acc);
      acc = MFu(h1, Bh1, acc);
      acc = MFu(h1, Bl1, acc);
      acc = MFu(l1_, Bh1, acc);
      const int sh = 4 * t + shb;
      float s0 = ((mw0 >> sh) & 1u) ? 0.f : acc.x;
      float s1 = ((mw1 >> sh) & 1u) ? 0.f : acc.y;
      float s2 = ((mw2 >> sh) & 1u) ? 0.f : acc.z;
      float s3 = ((mw3 >> sh) & 1u) ? 0.f : acc.w;
      rs += (s0 + s1) + (s2 + s3);
      H1 p0, p1;
      p0.h = pkrtz(s0, s1); p1.h = pkrtz(s2, s3);
      su[win][t][0] = p0.u; su[win][t][1] = p1.u;
    }
    __syncthreads();   // win+1 DMA complete; buffer free for win+2
  }

  // ---- dinv: row-sum across quads + 4 ks-waves ----
  rs += __shfl_xor(rs, 16);
  rs += __shfl_xor(rs, 32);
  if (l < 16) red[16 * qt + ln][ks] = rs;
  __syncthreads();
  if (tid < 32) {
    f32x4 r4 = *(const f32x4*)&red[tid][0];
    float s = (r4.x + r4.y) + (r4.z + r4.w);
    dinv_s[tid] = 1.0f / fmaxf(s, 1e-14f);
  }
  __syncthreads();

  // ---- loop2: per window {Vq prefetch ∥ attn stores from regs ∥ PV MFMA} ----
  // Stores issue early; 8 windows of Vq latency + MFMA drain them.
  f32x4 pv[4] = {{0,0,0,0},{0,0,0,0},{0,0,0,0},{0,0,0,0}};
  const float dv = dinv_s[16 * qt + ln];
  float* arow = outA + (size_t)(b * Lq + q0 + 16 * qt + ln) * Lq + ks * 64;

  u32x4 vb[2][8];
#pragma unroll
  for (int g2 = 0; g2 < 2; ++g2)
#pragma unroll
    for (int nt = 0; nt < 4; ++nt)
      vb[0][g2 * 4 + nt] =
          Vqp[(size_t)(b * 8) * 2048 + (((ks * 2 + g2) * 4 + u) * 4 + nt) * 16 + ln];

#pragma unroll
  for (int win = 0; win < 8; ++win) {
    const int c2 = win & 1;
    if (win < 7) {
      const u32x4* vqn = Vqp + (size_t)(b * 8 + win + 1) * 2048;
#pragma unroll
      for (int g2 = 0; g2 < 2; ++g2)
#pragma unroll
        for (int nt = 0; nt < 4; ++nt)
          vb[c2 ^ 1][g2 * 4 + nt] = vqn[(((ks * 2 + g2) * 4 + u) * 4 + nt) * 16 + ln];
    }
    // attn stores for this window (256B-aligned contiguous chunk per row)
#pragma unroll
    for (int t = 0; t < 4; ++t) {
      H1 p0, p1; p0.u = su[win][t][0]; p1.u = su[win][t][1];
      f32x4 st = {(float)p0.h.x * dv, (float)p0.h.y * dv,
                  (float)p1.h.x * dv, (float)p1.h.y * dv};
      __builtin_nontemporal_store(st, (f32x4*)(arow + win * 256 + 16 * t + 4 * u));
    }
    // PV for this window
#pragma unroll
    for (int g2 = 0; g2 < 2; ++g2) {
      H8 aw;
      aw.u[0] = su[win][2 * g2][0];     aw.u[1] = su[win][2 * g2][1];
      aw.u[2] = su[win][2 * g2 + 1][0]; aw.u[3] = su[win][2 * g2 + 1][1];
      pv[0] = MF16(aw.v8, __builtin_bit_cast(f16x8, vb[c2][g2 * 4 + 0]), pv[0]);
      pv[1] = MF16(aw.v8, __builtin_bit_cast(f16x8, vb[c2][g2 * 4 + 1]), pv[1]);
      pv[2] = MF16(aw.v8, __builtin_bit_cast(f16x8, vb[c2][g2 * 4 + 2]), pv[2]);
      pv[3] = MF16(aw.v8, __builtin_bit_cast(f16x8, vb[c2][g2 * 4 + 3]), pv[3]);
    }
  }

  // ---- cross-ks O reduction (kbuf[0] free since loop1) + store ----
  {
    float (*Or)[4][16][66] = (float (*)[4][16][66])&kbuf[0][0];
#pragma unroll
    for (int nt = 0; nt < 4; ++nt)
#pragma unroll
      for (int r2 = 0; r2 < 4; ++r2)
        Or[qt][ks][4 * u + r2][16 * nt + ln] = pv[nt][r2];
    __syncthreads();
#pragma unroll
    for (int i = 0; i < 2; ++i) {
      int item = tid + NT * i;
      int q_ = item >> 5, d = (item & 31) * 2;
      float o0 = 0.f, o1 = 0.f;
#pragma unroll
      for (int k2 = 0; k2 < 4; ++k2) {
        o0 += Or[q_ >> 4][k2][q_ & 15][d];
        o1 += Or[q_ >> 4][k2][q_ & 15][d + 1];
      }
      float dvq = dinv_s[q_];
      f32x2 st = {o0 * dvq, o1 * dvq};
      *(f32x2*)(outO + (size_t)(b * Lq + q0 + q_) * Dd + d) = st;
    }
  }
}

extern "C" void kernel_launch(void* const* d_in, const int* in_sizes, int n_in,
                              void* d_out, int out_size, void* d_ws, size_t ws_size,
                              hipStream_t stream) {
  const float* q = (const float*)d_in[0];
  const float* k = (const float*)d_in[1];
  const float* v = (const float*)d_in[2];
  const int*   m = (const int*)d_in[3];
  float* outO = (float*)d_out;
  float* outA = outO + (size_t)Bb * Lq * Dd;

  char* ws = (char*)d_ws;
  u32x4* Kw4 = (u32x4*)ws;                    // 8 MB swizzled K h/l windows
  u32x4* Vq  = (u32x4*)(ws + (8u << 20));     // 4 MB V B-frags
  u64*   mb  = (u64*)(ws + (12u << 20));      // 8 MB mask bitplanes
  sdpa_prep<<<4096, 256, 0, stream>>>(k, v, (const i32x4*)m, Kw4, Vq, mb);
  sdpa_main<<<Bb * (Lq / QT), NT, 0, stream>>>(q, (const char*)Kw4, Vq, mb, outO, outA);
}

// Round 11
// 171.441 us; speedup vs baseline: 1.0880x; 1.0880x over previous
//
#include <hip/hip_runtime.h>

#define Bb 16
#define Lq 2048
#define Dd 64
#define QT 32          // q-rows per block
#define NT 512         // 8 waves: (qt = w>>2, ks = w&3)

typedef _Float16 f16x2 __attribute__((ext_vector_type(2)));
typedef _Float16 f16x8 __attribute__((ext_vector_type(8)));
typedef __attribute__((ext_vector_type(4))) float f32x4;
typedef __attribute__((ext_vector_type(2))) float f32x2;
typedef __attribute__((ext_vector_type(4))) unsigned int u32x4;
typedef __attribute__((ext_vector_type(2))) unsigned int u32x2;
typedef __attribute__((ext_vector_type(4))) int i32x4;
typedef unsigned long long u64;
typedef __attribute__((ext_vector_type(2))) unsigned long long u64x2;

union H8 { f16x8 v8; f16x2 h2[4]; unsigned int u[4]; u32x4 u4; };
union H1 { f16x2 h; unsigned int u; };

__device__ __forceinline__ f16x2 pkrtz(float a, float b) {
  return __builtin_bit_cast(f16x2, __builtin_amdgcn_cvt_pkrtz(a, b));
}
__device__ __forceinline__ f32x4 MF16(f16x8 a, f16x8 b, f32x4 c) {
  return __builtin_amdgcn_mfma_f32_16x16x32_f16(a, b, c, 0, 0, 0);
}
__device__ __forceinline__ f32x4 MFu(u32x4 a, const H8& b, f32x4 c) {
  return MF16(__builtin_bit_cast(f16x8, a), b.v8, c);
}
// async global->LDS DMA, 16B/lane; dst wave-uniform base (+lane*16 by HW)
__device__ __forceinline__ void gl_lds16(const void* g, void* l) {
  __builtin_amdgcn_global_load_lds(
      (const __attribute__((address_space(1))) void*)g,
      (__attribute__((address_space(3))) void*)l, 16, 0, 0);
}

// ---- prep: K -> interleaved h/l 64KB windows, slot-swizzled (linear DMA +
//      swizzled ds_read = both-sides rule); V -> B-frag order; mask -> bitplanes
__global__ __launch_bounds__(256)
void sdpa_prep(const float* __restrict__ kg, const float* __restrict__ vg,
               const i32x4* __restrict__ mg4,
               u32x4* __restrict__ Kw4, u32x4* __restrict__ Vq,
               u64* __restrict__ mb)
{
  const int t = threadIdx.x, blk = blockIdx.x;
  if (blk < 1024) {                        // K: 32 rows/block, 8 octets/row
    const int row = blk * 32 + (t >> 3);
    const int oct = t & 7;
    const int b = row >> 11, r = row & 2047;
    const int win = r >> 8, rw = r & 255;
    const float* kp = kg + (size_t)row * Dd + oct * 8;
    f32x4 a = *(const f32x4*)kp;
    f32x4 c = *(const f32x4*)(kp + 4);
    H1 h0, h1, h2, h3, l0, l1, l2, l3;
    h0.h = pkrtz(a.x, a.y); l0.h = pkrtz(a.x - (float)h0.h.x, a.y - (float)h0.h.y);
    h1.h = pkrtz(a.z, a.w); l1.h = pkrtz(a.z - (float)h1.h.x, a.w - (float)h1.h.y);
    h2.h = pkrtz(c.x, c.y); l2.h = pkrtz(c.x - (float)h2.h.x, c.y - (float)h2.h.y);
    h3.h = pkrtz(c.z, c.w); l3.h = pkrtz(c.z - (float)h3.h.x, c.w - (float)h3.h.y);
    u32x4 hh = {h0.u, h1.u, h2.u, h3.u};
    u32x4 ll = {l0.u, l1.u, l2.u, l3.u};
    const int sl = oct ^ (rw & 7);
    const size_t base = ((size_t)((b * 8 + win) * 256 + rw)) * 16;
    Kw4[base + sl] = hh;
    Kw4[base + 8 + sl] = ll;
  } else if (blk < 2048) {                 // V: one B-frag u32x4/thread
    const int v_ = (blk - 1024) * 256 + t;
    const int ln = v_ & 15, nt = (v_ >> 4) & 3, u = (v_ >> 6) & 3;
    const int g = (v_ >> 8) & 7, w = (v_ >> 11) & 7, b = v_ >> 14;
    const int R = w * 256 + g * 32 + u * 4;
    const float* vp = vg + ((size_t)b * Lq + R) * Dd + nt * 16 + ln;
    H1 p0, p1, p2, p3;
    p0.h = pkrtz(vp[0 * Dd],  vp[1 * Dd]);
    p1.h = pkrtz(vp[2 * Dd],  vp[3 * Dd]);
    p2.h = pkrtz(vp[16 * Dd], vp[17 * Dd]);
    p3.h = pkrtz(vp[18 * Dd], vp[19 * Dd]);
    u32x4 o = {p0.u, p1.u, p2.u, p3.u};
    Vq[v_] = o;
  } else {                                 // mask: window=256 cols -> 4 u64 ballots
    const int l  = t & 63;
    const int wg = ((blk - 2048) << 2) | (t >> 6);
    i32x4 cur = __builtin_nontemporal_load(&mg4[((size_t)wg * 32) * 64 + l]);
#pragma unroll 1
    for (int it = 0; it < 32; ++it) {
      i32x4 nxt = {0, 0, 0, 0};
      if (it < 31) nxt = __builtin_nontemporal_load(&mg4[((size_t)wg * 32 + it + 1) * 64 + l]);
      u64 b0 = __ballot(cur.x != 0);
      u64 b1 = __ballot(cur.y != 0);
      u64 b2 = __ballot(cur.z != 0);
      u64 b3 = __ballot(cur.w != 0);
      if (l == 0) {
        u64* o = mb + ((size_t)wg * 32 + it) * 4;
        u64x2 w0 = {b0, b1}, w1 = {b2, b3};
        *(u64x2*)o = w0;
        *(u64x2*)(o + 2) = w1;
      }
      cur = nxt;
    }
  }
}

// ---------------------------- main kernel ----------------------------
__global__ __launch_bounds__(NT, 2)
void sdpa_main(const float* __restrict__ qg, const char* __restrict__ Kw,
               const u32x4* __restrict__ Vqp, const u64* __restrict__ mbp,
               float* __restrict__ outO, float* __restrict__ outA)
{
  __shared__ char kbuf[2][65536];                   // K-window double buffer
  __shared__ unsigned int Qh[QT][36], Ql[QT][36];   // 9.2 KB
  __shared__ float red[QT][4];
  __shared__ float dinv_s[QT];

  const int tid = threadIdx.x;
  const int l   = tid & 63;
  const int ln  = l & 15;
  const int u   = l >> 4;
  const int w   = tid >> 6;        // 0..7
  const int qt  = w >> 2;          // q-tile 0/1
  const int ks  = w & 3;           // k-quarter of window (64 rows)
  const int bid = (int)(blockIdx.x % 8) * 128 + (int)(blockIdx.x / 8); // XCD swz
  const int b   = bid >> 6;
  const int q0  = (bid & 63) * QT;

  // Phase 0: Q (32 rows) -> f16 h/l split planes in LDS
  {
    int r = tid >> 4, i4 = tid & 15;
    f32x4 qv = *(const f32x4*)(qg + (size_t)(b * Lq + q0 + r) * Dd + 4 * i4);
    H1 ha, hb, la, lb;
    ha.h = pkrtz(qv.x, qv.y); la.h = pkrtz(qv.x - (float)ha.h.x, qv.y - (float)ha.h.y);
    hb.h = pkrtz(qv.z, qv.w); lb.h = pkrtz(qv.z - (float)hb.h.x, qv.w - (float)hb.h.y);
    Qh[r][2 * i4] = ha.u; Qh[r][2 * i4 + 1] = hb.u;
    Ql[r][2 * i4] = la.u; Ql[r][2 * i4 + 1] = lb.u;
  }

  const char* kwb = Kw + (size_t)b * 8 * 65536;
  auto STAGE = [&](int buf_, int win_) {
#pragma unroll
    for (int i = 0; i < 8; ++i)
      gl_lds16(kwb + (size_t)win_ * 65536 + i * 8192 + w * 1024 + l * 16,
               &kbuf[buf_][i * 8192 + w * 1024]);
  };
  STAGE(0, 0);
  __syncthreads();   // prologue full drain: Q planes + window-0 DMA

  H8 Bh0, Bh1, Bl0, Bl1;
  Bh0.u4 = *(const u32x4*)&Qh[16 * qt + ln][4 * u];
  Bh1.u4 = *(const u32x4*)&Qh[16 * qt + ln][16 + 4 * u];
  Bl0.u4 = *(const u32x4*)&Ql[16 * qt + ln][4 * u];
  Bl1.u4 = *(const u32x4*)&Ql[16 * qt + ln][16 + 4 * u];

  const u64* mrow = mbp + (size_t)(b * Lq + q0 + 16 * qt + ln) * 32;
  unsigned int su[8][4][2];                 // S f16-pairs, whole k-range of wave
  f32x4 pv[4] = {{0,0,0,0},{0,0,0,0},{0,0,0,0},{0,0,0,0}};
  float rs = 0.f;
  const int key   = ln & 7;
  const int rbase = ks * 64;
  const int shb   = u + ((ks & 1) << 4);
  const bool lowh = (ks < 2);

  // ---- fused window loop, counted-vmcnt pipeline (no vmcnt(0) in loop) ----
  // Per window, vm ops in program order: [mask 2][Vq 8][STAGE(win+1) 8].
  // vmcnt(18) at win<7 (vmcnt(10) at win 7) => previous window's STAGE retired
  // (kbuf[cur] ready) while this window's 18 stay in flight. Compiler's own
  // waits then retire mask at vmcnt(16) and Vq at vmcnt(8) -- FIFO order --
  // leaving STAGE(win+1) airborne across the whole window's compute.
#pragma unroll
  for (int win = 0; win < 8; ++win) {
    const int cur = win & 1;
    asm volatile("s_waitcnt lgkmcnt(0)" ::: "memory");  // own ds_reads done
    __builtin_amdgcn_sched_barrier(0);
    __builtin_amdgcn_s_barrier();            // all waves done with kbuf[cur^1]

    u32x4 MA = *(const u32x4*)(mrow + win * 4);          // 2 vm ops
    u32x4 MC = *(const u32x4*)(mrow + win * 4 + 2);
    u32x4 vbuf[8];                                        // 8 vm ops
    const u32x4* vq = Vqp + (size_t)(b * 8 + win) * 2048;
#pragma unroll
    for (int g2 = 0; g2 < 2; ++g2)
#pragma unroll
      for (int nt = 0; nt < 4; ++nt)
        vbuf[g2 * 4 + nt] = vq[(((ks * 2 + g2) * 4 + u) * 4 + nt) * 16 + ln];

    if (win < 7) {
      STAGE(cur ^ 1, win + 1);                            // 8 vm ops
      asm volatile("s_waitcnt vmcnt(18)" ::: "memory");   // prev STAGE retired
    } else {
      asm volatile("s_waitcnt vmcnt(10)" ::: "memory");   // STAGE(7) retired
    }

    unsigned mw0 = lowh ? MA.x : MA.y;
    unsigned mw1 = lowh ? MA.z : MA.w;
    unsigned mw2 = lowh ? MC.x : MC.y;
    unsigned mw3 = lowh ? MC.z : MC.w;

    const char* kb_ = &kbuf[cur][0];
#pragma unroll
    for (int t = 0; t < 4; ++t) {
      const int rw = rbase + 16 * t + ln;
      const char* rp = kb_ + rw * 256;
      u32x4 h0  = *(const u32x4*)(rp + ((u ^ key) << 4));
      u32x4 h1  = *(const u32x4*)(rp + (((4 + u) ^ key) << 4));
      u32x4 l0_ = *(const u32x4*)(rp + ((8 | (u ^ key)) << 4));
      u32x4 l1_ = *(const u32x4*)(rp + ((8 | ((4 + u) ^ key)) << 4));
      f32x4 acc = {0.f, 0.f, 0.f, 0.f};
      acc = MFu(h0, Bh0, acc);
      acc = MFu(h0, Bl0, acc);
      acc = MFu(l0_, Bh0, acc);
      acc = MFu(h1, Bh1, acc);
      acc = MFu(h1, Bl1, acc);
      acc = MFu(l1_, Bh1, acc);
      const int sh = 4 * t + shb;
      float s0 = ((mw0 >> sh) & 1u) ? 0.f : acc.x;
      float s1 = ((mw1 >> sh) & 1u) ? 0.f : acc.y;
      float s2 = ((mw2 >> sh) & 1u) ? 0.f : acc.z;
      float s3 = ((mw3 >> sh) & 1u) ? 0.f : acc.w;
      rs += (s0 + s1) + (s2 + s3);
      H1 p0, p1;
      p0.h = pkrtz(s0, s1); p1.h = pkrtz(s2, s3);
      su[win][t][0] = p0.u; su[win][t][1] = p1.u;
    }
    // PV for this window (compiler waits vmcnt(8): Vq retired, STAGE flying)
#pragma unroll
    for (int g2 = 0; g2 < 2; ++g2) {
      H8 aw;
      aw.u[0] = su[win][2 * g2][0];     aw.u[1] = su[win][2 * g2][1];
      aw.u[2] = su[win][2 * g2 + 1][0]; aw.u[3] = su[win][2 * g2 + 1][1];
      pv[0] = MF16(aw.v8, __builtin_bit_cast(f16x8, vbuf[g2 * 4 + 0]), pv[0]);
      pv[1] = MF16(aw.v8, __builtin_bit_cast(f16x8, vbuf[g2 * 4 + 1]), pv[1]);
      pv[2] = MF16(aw.v8, __builtin_bit_cast(f16x8, vbuf[g2 * 4 + 2]), pv[2]);
      pv[3] = MF16(aw.v8, __builtin_bit_cast(f16x8, vbuf[g2 * 4 + 3]), pv[3]);
    }
  }

  // ---- row-sums -> dinv ----
  rs += __shfl_xor(rs, 16);
  rs += __shfl_xor(rs, 32);
  if (l < 16) red[16 * qt + ln][ks] = rs;
  __syncthreads();   // all waves past win7 reads; red visible; kbuf free

  // S -> LDS transpose buffer (aliases kbuf, both halves), XOR-swizzled 8B units
  {
    char* Sb = &kbuf[0][0];
    const int row = 16 * qt + ln;
    char* srow = Sb + row * 4096;
    const unsigned skey = (unsigned)(row & 15) << 3;
#pragma unroll
    for (int win = 0; win < 8; ++win)
#pragma unroll
      for (int t = 0; t < 4; ++t) {
        unsigned Bo = 512u * win + 128u * ks + 32u * t + 8u * u;
        u32x2 pk2 = {su[win][t][0], su[win][t][1]};
        *(u32x2*)(srow + (Bo ^ skey)) = pk2;
      }
  }
  if (tid < 32) {
    f32x4 r4 = *(const f32x4*)&red[tid][0];
    float s = (r4.x + r4.y) + (r4.z + r4.w);
    dinv_s[tid] = 1.0f / fmaxf(s, 1e-14f);
  }
  __syncthreads();

  // attn stores: 4 rows/wave, 1KB-contiguous nontemporal bursts (clean lines)
  {
    const char* Sb = &kbuf[0][0];
#pragma unroll
    for (int r = 0; r < 4; ++r) {
      const int rr = 4 * w + r;
      const float dv = dinv_s[rr];
      const char* sr = Sb + rr * 4096;
      const unsigned rk = (unsigned)(rr & 15) << 3;
      float* arow = outA + (size_t)(b * Lq + q0 + rr) * Lq;
#pragma unroll
      for (int m = 0; m < 8; ++m) {
        u32x2 pk = *(const u32x2*)(sr + ((unsigned)(512 * m + 8 * l) ^ rk));
        H1 a0, a1; a0.u = pk.x; a1.u = pk.y;
        f32x4 st = {(float)a0.h.x * dv, (float)a0.h.y * dv,
                    (float)a1.h.x * dv, (float)a1.h.y * dv};
        __builtin_nontemporal_store(st, (f32x4*)(arow + 256 * m + 4 * l));
      }
    }
  }
  __syncthreads();   // all Sb reads done -> Or may alias

  // cross-ks O reduction + store
  {
    float (*Or)[4][16][66] = (float (*)[4][16][66])&kbuf[0][0];
#pragma unroll
    for (int nt = 0; nt < 4; ++nt)
#pragma unroll
      for (int r2 = 0; r2 < 4; ++r2)
        Or[qt][ks][4 * u + r2][16 * nt + ln] = pv[nt][r2];
    __syncthreads();
#pragma unroll
    for (int i = 0; i < 2; ++i) {
      int item = tid + NT * i;
      int q_ = item >> 5, d = (item & 31) * 2;
      float o0 = 0.f, o1 = 0.f;
#pragma unroll
      for (int k2 = 0; k2 < 4; ++k2) {
        o0 += Or[q_ >> 4][k2][q_ & 15][d];
        o1 += Or[q_ >> 4][k2][q_ & 15][d + 1];
      }
      float dvq = dinv_s[q_];
      f32x2 st = {o0 * dvq, o1 * dvq};
      *(f32x2*)(outO + (size_t)(b * Lq + q0 + q_) * Dd + d) = st;
    }
  }
}

extern "C" void kernel_launch(void* const* d_in, const int* in_sizes, int n_in,
                              void* d_out, int out_size, void* d_ws, size_t ws_size,
                              hipStream_t stream) {
  const float* q = (const float*)d_in[0];
  const float* k = (const float*)d_in[1];
  const float* v = (const float*)d_in[2];
  const int*   m = (const int*)d_in[3];
  float* outO = (float*)d_out;
  float* outA = outO + (size_t)Bb * Lq * Dd;

  char* ws = (char*)d_ws;
  u32x4* Kw4 = (u32x4*)ws;                    // 8 MB swizzled K h/l windows
  u32x4* Vq  = (u32x4*)(ws + (8u << 20));     // 4 MB V B-frags
  u64*   mb  = (u64*)(ws + (12u << 20));      // 8 MB mask bitplanes
  sdpa_prep<<<4096, 256, 0, stream>>>(k, v, (const i32x4*)m, Kw4, Vq, mb);
  sdpa_main<<<Bb * (Lq / QT), NT, 0, stream>>>(q, (const char*)Kw4, Vq, mb, outO, outA);
}

// Round 12
// 169.711 us; speedup vs baseline: 1.0991x; 1.0102x over previous
//
#include <hip/hip_runtime.h>

#define Bb 16
#define Lq 2048
#define Dd 64
#define QT 32          // q-rows per block
#define NT 512         // 8 waves: (qt = w>>2, ks = w&3)
#define NWIN 16        // 16 windows of 128 k-rows
#define WINB 32768     // 32 KB per K window (128 rows x 256 B)

typedef _Float16 f16x2 __attribute__((ext_vector_type(2)));
typedef _Float16 f16x8 __attribute__((ext_vector_type(8)));
typedef __attribute__((ext_vector_type(4))) float f32x4;
typedef __attribute__((ext_vector_type(2))) float f32x2;
typedef __attribute__((ext_vector_type(4))) unsigned int u32x4;
typedef __attribute__((ext_vector_type(2))) unsigned int u32x2;
typedef __attribute__((ext_vector_type(4))) int i32x4;
typedef unsigned long long u64;
typedef __attribute__((ext_vector_type(2))) unsigned long long u64x2;

union H8 { f16x8 v8; f16x2 h2[4]; unsigned int u[4]; u32x4 u4; };
union H1 { f16x2 h; unsigned int u; };

__device__ __forceinline__ f16x2 pkrtz(float a, float b) {
  return __builtin_bit_cast(f16x2, __builtin_amdgcn_cvt_pkrtz(a, b));
}
__device__ __forceinline__ f32x4 MF16(f16x8 a, f16x8 b, f32x4 c) {
  return __builtin_amdgcn_mfma_f32_16x16x32_f16(a, b, c, 0, 0, 0);
}
__device__ __forceinline__ f32x4 MFu(u32x4 a, const H8& b, f32x4 c) {
  return MF16(__builtin_bit_cast(f16x8, a), b.v8, c);
}
// async global->LDS DMA, 16B/lane; dst wave-uniform base (+lane*16 by HW)
__device__ __forceinline__ void gl_lds16(const void* g, void* l) {
  __builtin_amdgcn_global_load_lds(
      (const __attribute__((address_space(1))) void*)g,
      (__attribute__((address_space(3))) void*)l, 16, 0, 0);
}

// ---- prep: K -> h/l 32KB windows, slot-swizzled (linear DMA + swizzled
//      ds_read = both-sides rule); V -> B-frag order; mask -> bitplanes ----
__global__ __launch_bounds__(256)
void sdpa_prep(const float* __restrict__ kg, const float* __restrict__ vg,
               const i32x4* __restrict__ mg4,
               u32x4* __restrict__ Kw4, u32x4* __restrict__ Vq,
               u64* __restrict__ mb)
{
  const int t = threadIdx.x, blk = blockIdx.x;
  if (blk < 1024) {                        // K: 32 rows/block, 8 octets/row
    const int row = blk * 32 + (t >> 3);
    const int oct = t & 7;
    const int b = row >> 11, r = row & 2047;
    const int win = r >> 7, rw = r & 127;  // 16 windows of 128 rows
    const float* kp = kg + (size_t)row * Dd + oct * 8;
    f32x4 a = *(const f32x4*)kp;
    f32x4 c = *(const f32x4*)(kp + 4);
    H1 h0, h1, h2, h3, l0, l1, l2, l3;
    h0.h = pkrtz(a.x, a.y); l0.h = pkrtz(a.x - (float)h0.h.x, a.y - (float)h0.h.y);
    h1.h = pkrtz(a.z, a.w); l1.h = pkrtz(a.z - (float)h1.h.x, a.w - (float)h1.h.y);
    h2.h = pkrtz(c.x, c.y); l2.h = pkrtz(c.x - (float)h2.h.x, c.y - (float)h2.h.y);
    h3.h = pkrtz(c.z, c.w); l3.h = pkrtz(c.z - (float)h3.h.x, c.w - (float)h3.h.y);
    u32x4 hh = {h0.u, h1.u, h2.u, h3.u};
    u32x4 ll = {l0.u, l1.u, l2.u, l3.u};
    const int sl = oct ^ (rw & 7);
    const size_t base = ((size_t)((b * 16 + win) * 128 + rw)) * 16;
    Kw4[base + sl] = hh;
    Kw4[base + 8 + sl] = ll;
  } else if (blk < 2048) {                 // V: one B-frag u32x4/thread
    const int v_ = (blk - 1024) * 256 + t;
    const int ln = v_ & 15, nt = (v_ >> 4) & 3, u = (v_ >> 6) & 3;
    const int g = (v_ >> 8) & 7, w = (v_ >> 11) & 7, b = v_ >> 14;
    const int R = w * 256 + g * 32 + u * 4;
    const float* vp = vg + ((size_t)b * Lq + R) * Dd + nt * 16 + ln;
    H1 p0, p1, p2, p3;
    p0.h = pkrtz(vp[0 * Dd],  vp[1 * Dd]);
    p1.h = pkrtz(vp[2 * Dd],  vp[3 * Dd]);
    p2.h = pkrtz(vp[16 * Dd], vp[17 * Dd]);
    p3.h = pkrtz(vp[18 * Dd], vp[19 * Dd]);
    u32x4 o = {p0.u, p1.u, p2.u, p3.u};
    Vq[v_] = o;
  } else {                                 // mask: window=256 cols -> 4 u64 ballots
    const int l  = t & 63;
    const int wg = ((blk - 2048) << 2) | (t >> 6);
    i32x4 cur = __builtin_nontemporal_load(&mg4[((size_t)wg * 32) * 64 + l]);
#pragma unroll 1
    for (int it = 0; it < 32; ++it) {
      i32x4 nxt = {0, 0, 0, 0};
      if (it < 31) nxt = __builtin_nontemporal_load(&mg4[((size_t)wg * 32 + it + 1) * 64 + l]);
      u64 b0 = __ballot(cur.x != 0);
      u64 b1 = __ballot(cur.y != 0);
      u64 b2 = __ballot(cur.z != 0);
      u64 b3 = __ballot(cur.w != 0);
      if (l == 0) {
        u64* o = mb + ((size_t)wg * 32 + it) * 4;
        u64x2 w0 = {b0, b1}, w1 = {b2, b3};
        *(u64x2*)o = w0;
        *(u64x2*)(o + 2) = w1;
      }
      cur = nxt;
    }
  }
}

// ---------------------------- main kernel ----------------------------
// LDS: kbuf 64K + Q planes 9.2K + red/dinv ~0.7K = ~74 KB -> 2 blocks/CU.
__global__ __launch_bounds__(NT, 4)
void sdpa_main(const float* __restrict__ qg, const char* __restrict__ Kw,
               const u32x4* __restrict__ Vqp, const u64* __restrict__ mbp,
               float* __restrict__ outO, float* __restrict__ outA)
{
  __shared__ char kbuf[2][WINB];                    // 64 KB K-window dbuf
  __shared__ unsigned int Qh[QT][36], Ql[QT][36];   // 9.2 KB
  __shared__ float red[QT][4];
  __shared__ float dinv_s[QT];

  const int tid = threadIdx.x;
  const int l   = tid & 63;
  const int ln  = l & 15;
  const int u   = l >> 4;
  const int w   = tid >> 6;        // 0..7
  const int qt  = w >> 2;          // q-tile 0/1
  const int ks  = w & 3;           // k-quarter of window (32 rows)
  const int bid = (int)(blockIdx.x % 8) * 128 + (int)(blockIdx.x / 8); // XCD swz
  const int b   = bid >> 6;
  const int q0  = (bid & 63) * QT;

  // Phase 0: Q (32 rows) -> f16 h/l split planes in LDS
  {
    int r = tid >> 4, i4 = tid & 15;
    f32x4 qv = *(const f32x4*)(qg + (size_t)(b * Lq + q0 + r) * Dd + 4 * i4);
    H1 ha, hb, la, lb;
    ha.h = pkrtz(qv.x, qv.y); la.h = pkrtz(qv.x - (float)ha.h.x, qv.y - (float)ha.h.y);
    hb.h = pkrtz(qv.z, qv.w); lb.h = pkrtz(qv.z - (float)hb.h.x, qv.w - (float)hb.h.y);
    Qh[r][2 * i4] = ha.u; Qh[r][2 * i4 + 1] = hb.u;
    Ql[r][2 * i4] = la.u; Ql[r][2 * i4 + 1] = lb.u;
  }

  const char* kwb = Kw + (size_t)b * NWIN * WINB;
  auto STAGE = [&](int buf_, int win_) {
#pragma unroll
    for (int i = 0; i < 4; ++i)
      gl_lds16(kwb + (size_t)win_ * WINB + i * 8192 + w * 1024 + l * 16,
               &kbuf[buf_][i * 8192 + w * 1024]);
  };
  STAGE(0, 0);
  __syncthreads();   // Q planes + window-0 DMA drained

  H8 Bh0, Bh1, Bl0, Bl1;
  Bh0.u4 = *(const u32x4*)&Qh[16 * qt + ln][4 * u];
  Bh1.u4 = *(const u32x4*)&Qh[16 * qt + ln][16 + 4 * u];
  Bl0.u4 = *(const u32x4*)&Ql[16 * qt + ln][4 * u];
  Bl1.u4 = *(const u32x4*)&Ql[16 * qt + ln][16 + 4 * u];

  const u64* mrow = mbp + (size_t)(b * Lq + q0 + 16 * qt + ln) * 32;
  unsigned int su[NWIN][2][2];              // S f16-pairs (64 regs)
  f32x4 pv[4] = {{0,0,0,0},{0,0,0,0},{0,0,0,0},{0,0,0,0}};
  float rs = 0.f;
  const int key   = ln & 7;
  const int rbase = ks * 32;
  u32x4 MA, MC;

  // ---- fused window loop (R9 discipline: syncthreads per window) ----
#pragma unroll
  for (int win = 0; win < NWIN; ++win) {
    const int cur = win & 1;
    if (win < NWIN - 1) STAGE(cur ^ 1, win + 1);

    if ((win & 1) == 0) {                   // mask bitplanes per window-pair
      MA = *(const u32x4*)(mrow + (win >> 1) * 4);
      MC = *(const u32x4*)(mrow + (win >> 1) * 4 + 2);
    }
    // word j, u32-half = win&1, bit = ks*8 + 4t + u
    unsigned mw0 = (win & 1) ? MA.y : MA.x;
    unsigned mw1 = (win & 1) ? MA.w : MA.z;
    unsigned mw2 = (win & 1) ? MC.y : MC.x;
    unsigned mw3 = (win & 1) ? MC.w : MC.z;

    // Vq loads for this window (4 x 16B, L2) — covered by QK^T MFMAs
    u32x4 vbuf[4];
    {
      const u32x4* vq = Vqp + (size_t)(b * 8 + (win >> 1)) * 2048;
      const int g_old = (win & 1) * 4 + ks;
#pragma unroll
      for (int nt = 0; nt < 4; ++nt)
        vbuf[nt] = vq[((g_old * 4 + u) * 4 + nt) * 16 + ln];
    }

    const char* kb_ = &kbuf[cur][0];
#pragma unroll
    for (int t = 0; t < 2; ++t) {
      const int rw = rbase + 16 * t + ln;
      const char* rp = kb_ + rw * 256;
      u32x4 h0  = *(const u32x4*)(rp + ((u ^ key) << 4));
      u32x4 h1  = *(const u32x4*)(rp + (((4 + u) ^ key) << 4));
      u32x4 l0_ = *(const u32x4*)(rp + ((8 | (u ^ key)) << 4));
      u32x4 l1_ = *(const u32x4*)(rp + ((8 | ((4 + u) ^ key)) << 4));
      f32x4 acc = {0.f, 0.f, 0.f, 0.f};
      acc = MFu(h0, Bh0, acc);
      acc = MFu(h0, Bl0, acc);
      acc = MFu(l0_, Bh0, acc);
      acc = MFu(h1, Bh1, acc);
      acc = MFu(h1, Bl1, acc);
      acc = MFu(l1_, Bh1, acc);
      const int sh = ks * 8 + 4 * t + u;
      float s0 = ((mw0 >> sh) & 1u) ? 0.f : acc.x;
      float s1 = ((mw1 >> sh) & 1u) ? 0.f : acc.y;
      float s2 = ((mw2 >> sh) & 1u) ? 0.f : acc.z;
      float s3 = ((mw3 >> sh) & 1u) ? 0.f : acc.w;
      rs += (s0 + s1) + (s2 + s3);
      H1 p0, p1;
      p0.h = pkrtz(s0, s1); p1.h = pkrtz(s2, s3);
      su[win][t][0] = p0.u; su[win][t][1] = p1.u;
    }
    // PV for this window (one A-frag, 4 MFMA)
    {
      H8 aw;
      aw.u[0] = su[win][0][0]; aw.u[1] = su[win][0][1];
      aw.u[2] = su[win][1][0]; aw.u[3] = su[win][1][1];
      pv[0] = MF16(aw.v8, __builtin_bit_cast(f16x8, vbuf[0]), pv[0]);
      pv[1] = MF16(aw.v8, __builtin_bit_cast(f16x8, vbuf[1]), pv[1]);
      pv[2] = MF16(aw.v8, __builtin_bit_cast(f16x8, vbuf[2]), pv[2]);
      pv[3] = MF16(aw.v8, __builtin_bit_cast(f16x8, vbuf[3]), pv[3]);
    }
    __syncthreads();   // win+1 DMA drained; buffer free for win+2
  }

  // ---- row-sums -> dinv ----
  rs += __shfl_xor(rs, 16);
  rs += __shfl_xor(rs, 32);
  if (l < 16) red[16 * qt + ln][ks] = rs;
  __syncthreads();
  if (tid < 32) {
    f32x4 r4 = *(const f32x4*)&red[tid][0];
    float s = (r4.x + r4.y) + (r4.z + r4.w);
    dinv_s[tid] = 1.0f / fmaxf(s, 1e-14f);
  }
  __syncthreads();

  // ---- attn stores in two 16-row half passes (Sb = 64 KB = kbuf alias) ----
  char* Sb = &kbuf[0][0];
#pragma unroll
  for (int half = 0; half < 2; ++half) {
    if (qt == half) {               // writers: waves of this q-half
      char* srow = Sb + ln * 4096;
      const unsigned skey = (unsigned)ln << 3;
#pragma unroll
      for (int win = 0; win < NWIN; ++win)
#pragma unroll
        for (int t = 0; t < 2; ++t) {
          unsigned Bo = 256u * win + 64u * ks + 32u * t + 8u * u;
          u32x2 pk2 = {su[win][t][0], su[win][t][1]};
          *(u32x2*)(srow + (Bo ^ skey)) = pk2;
        }
    }
    __syncthreads();
    // all 8 waves store: 2 rows/wave, 1KB-contiguous nontemporal bursts
#pragma unroll
    for (int r = 0; r < 2; ++r) {
      const int rl = 2 * w + r;             // row within half (0..15)
      const int rr = 16 * half + rl;        // global row (0..31)
      const float dv = dinv_s[rr];
      const char* sr = Sb + rl * 4096;
      const unsigned rk = (unsigned)rl << 3;
      float* arow = outA + (size_t)(b * Lq + q0 + rr) * Lq;
#pragma unroll
      for (int m = 0; m < 8; ++m) {
        u32x2 pk = *(const u32x2*)(sr + ((unsigned)(512 * m + 8 * l) ^ rk));
        H1 a0, a1; a0.u = pk.x; a1.u = pk.y;
        f32x4 st = {(float)a0.h.x * dv, (float)a0.h.y * dv,
                    (float)a1.h.x * dv, (float)a1.h.y * dv};
        __builtin_nontemporal_store(st, (f32x4*)(arow + 256 * m + 4 * l));
      }
    }
    __syncthreads();   // all Sb reads done -> next half may overwrite
  }

  // ---- cross-ks O reduction (kbuf alias) + store ----
  {
    float (*Or)[4][16][66] = (float (*)[4][16][66])&kbuf[0][0];
#pragma unroll
    for (int nt = 0; nt < 4; ++nt)
#pragma unroll
      for (int r2 = 0; r2 < 4; ++r2)
        Or[qt][ks][4 * u + r2][16 * nt + ln] = pv[nt][r2];
    __syncthreads();
#pragma unroll
    for (int i = 0; i < 2; ++i) {
      int item = tid + NT * i;
      int q_ = item >> 5, d = (item & 31) * 2;
      float o0 = 0.f, o1 = 0.f;
#pragma unroll
      for (int k2 = 0; k2 < 4; ++k2) {
        o0 += Or[q_ >> 4][k2][q_ & 15][d];
        o1 += Or[q_ >> 4][k2][q_ & 15][d + 1];
      }
      float dvq = dinv_s[q_];
      f32x2 st = {o0 * dvq, o1 * dvq};
      *(f32x2*)(outO + (size_t)(b * Lq + q0 + q_) * Dd + d) = st;
    }
  }
}

extern "C" void kernel_launch(void* const* d_in, const int* in_sizes, int n_in,
                              void* d_out, int out_size, void* d_ws, size_t ws_size,
                              hipStream_t stream) {
  const float* q = (const float*)d_in[0];
  const float* k = (const float*)d_in[1];
  const float* v = (const float*)d_in[2];
  const int*   m = (const int*)d_in[3];
  float* outO = (float*)d_out;
  float* outA = outO + (size_t)Bb * Lq * Dd;

  char* ws = (char*)d_ws;
  u32x4* Kw4 = (u32x4*)ws;                    // 8 MB swizzled K h/l windows
  u32x4* Vq  = (u32x4*)(ws + (8u << 20));     // 4 MB V B-frags
  u64*   mb  = (u64*)(ws + (12u << 20));      // 8 MB mask bitplanes
  sdpa_prep<<<4096, 256, 0, stream>>>(k, v, (const i32x4*)m, Kw4, Vq, mb);
  sdpa_main<<<Bb * (Lq / QT), NT, 0, stream>>>(q, (const char*)Kw4, Vq, mb, outO, outA);
}

// Round 13
// 161.081 us; speedup vs baseline: 1.1579x; 1.0536x over previous
//
#include <hip/hip_runtime.h>

#define Bb 16
#define Lq 2048
#define Dd 64
#define QT 16          // q-rows per block
#define NT 512         // 8 waves, each owns k-slice ks = w (16 rows/window)
#define NWIN 16        // 16 windows of 128 k-rows
#define WINB 32768     // 32 KB per K window (128 rows x 256 B)

typedef _Float16 f16x2 __attribute__((ext_vector_type(2)));
typedef _Float16 f16x8 __attribute__((ext_vector_type(8)));
typedef __attribute__((ext_vector_type(4))) float f32x4;
typedef __attribute__((ext_vector_type(2))) float f32x2;
typedef __attribute__((ext_vector_type(4))) unsigned int u32x4;
typedef __attribute__((ext_vector_type(2))) unsigned int u32x2;
typedef __attribute__((ext_vector_type(4))) int i32x4;
typedef unsigned long long u64;

union H8 { f16x8 v8; f16x2 h2[4]; unsigned int u[4]; u32x4 u4; };
union H1 { f16x2 h; unsigned int u; };

__device__ __forceinline__ f16x2 pkrtz(float a, float b) {
  return __builtin_bit_cast(f16x2, __builtin_amdgcn_cvt_pkrtz(a, b));
}
__device__ __forceinline__ f32x4 MF16(f16x8 a, f16x8 b, f32x4 c) {
  return __builtin_amdgcn_mfma_f32_16x16x32_f16(a, b, c, 0, 0, 0);
}
__device__ __forceinline__ f32x4 MFu(u32x4 a, const H8& b, f32x4 c) {
  return MF16(__builtin_bit_cast(f16x8, a), b.v8, c);
}
__device__ __forceinline__ void gl_lds16(const void* g, void* l) {
  __builtin_amdgcn_global_load_lds(
      (const __attribute__((address_space(1))) void*)g,
      (__attribute__((address_space(3))) void*)l, 16, 0, 0);
}

// ---- prep: K -> h/l 32KB windows slot-swizzled; V -> window-pair B-frag order
__global__ __launch_bounds__(256)
void sdpa_prep(const float* __restrict__ kg, const float* __restrict__ vg,
               u32x4* __restrict__ Kw4, u32x4* __restrict__ Vq)
{
  const int t = threadIdx.x, blk = blockIdx.x;
  if (blk < 1024) {                        // K: 32 rows/block, 8 octets/row
    const int row = blk * 32 + (t >> 3);
    const int oct = t & 7;
    const int b = row >> 11, r = row & 2047;
    const int win = r >> 7, rw = r & 127;  // 16 windows of 128 rows
    const float* kp = kg + (size_t)row * Dd + oct * 8;
    f32x4 a = *(const f32x4*)kp;
    f32x4 c = *(const f32x4*)(kp + 4);
    H1 h0, h1, h2, h3, l0, l1, l2, l3;
    h0.h = pkrtz(a.x, a.y); l0.h = pkrtz(a.x - (float)h0.h.x, a.y - (float)h0.h.y);
    h1.h = pkrtz(a.z, a.w); l1.h = pkrtz(a.z - (float)h1.h.x, a.w - (float)h1.h.y);
    h2.h = pkrtz(c.x, c.y); l2.h = pkrtz(c.x - (float)h2.h.x, c.y - (float)h2.h.y);
    h3.h = pkrtz(c.z, c.w); l3.h = pkrtz(c.z - (float)h3.h.x, c.w - (float)h3.h.y);
    u32x4 hh = {h0.u, h1.u, h2.u, h3.u};
    u32x4 ll = {l0.u, l1.u, l2.u, l3.u};
    const int sl = oct ^ (rw & 7);
    const size_t base = ((size_t)((b * 16 + win) * 128 + rw)) * 16;
    Kw4[base + sl] = hh;
    Kw4[base + 8 + sl] = ll;
  } else {                                 // V: window-pair B-frags
    const int v_ = (blk - 1024) * 256 + t;
    const int ln = v_ & 15, nt = (v_ >> 4) & 3, u = (v_ >> 6) & 3;
    const int ks = (v_ >> 8) & 7, g = (v_ >> 11) & 7, b = v_ >> 14;
    const int r0 = g * 256 + ks * 16 + 4 * u;     // win 2g rows; +128 = win 2g+1
    const float* vp = vg + ((size_t)b * Lq + r0) * Dd + nt * 16 + ln;
    H1 p0, p1, p2, p3;
    p0.h = pkrtz(vp[0],        vp[64]);           // k slots 0,1  (rows r0,r0+1)
    p1.h = pkrtz(vp[128],      vp[192]);          // k slots 2,3
    p2.h = pkrtz(vp[128 * 64], vp[129 * 64]);     // k slots 4,5  (rows r0+128,..)
    p3.h = pkrtz(vp[130 * 64], vp[131 * 64]);     // k slots 6,7
    u32x4 o = {p0.u, p1.u, p2.u, p3.u};
    Vq[v_] = o;
  }
}

// ---------------------------- main kernel ----------------------------
// LDS: kbuf 64K + Q/mask union 4.6K + red 0.6K  ->  ~69.3 KB => 2 blocks/CU.
__global__ __launch_bounds__(NT, 4)
void sdpa_main(const float* __restrict__ qg, const char* __restrict__ Kw,
               const u32x4* __restrict__ Vqp, const i32x4* __restrict__ mg4,
               float* __restrict__ outO, float* __restrict__ outA)
{
  __shared__ alignas(16) char kbuf[2][WINB];      // 64 KB K-window dbuf
  __shared__ alignas(16) char qmbuf[4624];        // Q planes, later mask bits
  __shared__ float red[QT][8];
  __shared__ float dinv_s[QT];

  unsigned int (*Qh)[36] = (unsigned int (*)[36])qmbuf;          // [16][36]
  unsigned int (*Ql)[36] = (unsigned int (*)[36])(qmbuf + 2304); // [16][36]
  u64 (*mbits)[34]       = (u64 (*)[34])qmbuf;                   // [16][34]

  const int tid = threadIdx.x;
  const int l   = tid & 63;
  const int ln  = l & 15;
  const int u   = l >> 4;
  const int w   = tid >> 6;        // 0..7 = ks (16 k-rows per window)
  const int bid = (int)(blockIdx.x % 8) * 256 + (int)(blockIdx.x / 8); // XCD swz
  const int b   = bid >> 7;
  const int q0  = (bid & 127) * QT;
  const int ks  = w;

  // Phase 0: Q (16 rows) -> f16 h/l split planes in LDS (512 thr, 2 f32 each)
  {
    int r = tid >> 5, d2 = tid & 31;
    f32x2 qv = *(const f32x2*)(qg + (size_t)(b * Lq + q0 + r) * Dd + 2 * d2);
    H1 h, lo;
    h.h  = pkrtz(qv.x, qv.y);
    lo.h = pkrtz(qv.x - (float)h.h.x, qv.y - (float)h.h.y);
    Qh[r][d2] = h.u;
    Ql[r][d2] = lo.u;
  }

  const char* kwb = Kw + (size_t)b * NWIN * WINB;
  auto STAGE = [&](int buf_, int win_) {
#pragma unroll
    for (int i = 0; i < 4; ++i)
      gl_lds16(kwb + (size_t)win_ * WINB + i * 8192 + w * 1024 + l * 16,
               &kbuf[buf_][i * 8192 + w * 1024]);
  };
  STAGE(0, 0);
  __syncthreads();                 // Q planes visible + window-0 DMA drained

  H8 Bh0, Bh1, Bl0, Bl1;
  Bh0.u4 = *(const u32x4*)&Qh[ln][4 * u];
  Bh1.u4 = *(const u32x4*)&Qh[ln][16 + 4 * u];
  Bl0.u4 = *(const u32x4*)&Ql[ln][4 * u];
  Bl1.u4 = *(const u32x4*)&Ql[ln][16 + 4 * u];
  __syncthreads();                 // all B-frag reads done before mask overwrite

  // Phase 0b: per-block mask pack (own 16 rows, 128 KB coalesced stream).
  // Window-pair W = 256 cols: word j covers cols c==j (mod 4), bit = c>>2.
  // Wave w packs rows 2w, 2w+1; lane l covers cols 4l..4l+3 of each 256-window.
#pragma unroll
  for (int i = 0; i < 2; ++i) {
    const int row = 2 * w + i;
    const size_t rbase = (size_t)(b * Lq + q0 + row) * 512;
#pragma unroll
    for (int W = 0; W < 8; ++W) {
      i32x4 mm = __builtin_nontemporal_load(&mg4[rbase + W * 64 + l]);
      u64 b0 = __ballot(mm.x != 0);
      u64 b1 = __ballot(mm.y != 0);
      u64 b2 = __ballot(mm.z != 0);
      u64 b3 = __ballot(mm.w != 0);
      if (l < 4) mbits[row][W * 4 + l] = (l == 0) ? b0 : (l == 1) ? b1 : (l == 2) ? b2 : b3;
    }
  }
  __syncthreads();

  unsigned int su[NWIN][2];        // S f16-pairs (32 regs)
  f32x4 pv[4] = {{0,0,0,0},{0,0,0,0},{0,0,0,0},{0,0,0,0}};
  float rs = 0.f;
  const int key = ln & 7;
  const int sh  = ks * 4 + u;      // bit within u32-half, per window parity
  u32x4 MA = {0,0,0,0}, MC = {0,0,0,0};
  u32x4 vbuf[4];

  // ---- fused window loop (16 windows of 128 k-rows) ----
#pragma unroll
  for (int win = 0; win < NWIN; ++win) {
    const int cur = win & 1;
    if (win < NWIN - 1) STAGE(cur ^ 1, win + 1);

    if ((win & 1) == 0) {
      const int g = win >> 1;
      const u64* mr = &mbits[ln][g * 4];          // 32B, broadcast across u
      MA = *(const u32x4*)mr;                     // words 0,1 (lo/hi 32b each)
      MC = *(const u32x4*)(mr + 2);               // words 2,3
      const u32x4* vq = Vqp + (size_t)b * 16384 + (((g * 8 + ks) * 4 + u) * 4) * 16 + ln;
#pragma unroll
      for (int nt = 0; nt < 4; ++nt) vbuf[nt] = vq[nt * 16];
    }
    unsigned mw0 = (win & 1) ? MA.y : MA.x;
    unsigned mw1 = (win & 1) ? MA.w : MA.z;
    unsigned mw2 = (win & 1) ? MC.y : MC.x;
    unsigned mw3 = (win & 1) ? MC.w : MC.z;

    // QK^T: rows rw = ks*16+ln of this window; 6 MFMA (hh,hl,lh over 2 halves)
    {
      const int rw = ks * 16 + ln;
      const char* rp = &kbuf[cur][0] + rw * 256;
      u32x4 h0  = *(const u32x4*)(rp + ((u ^ key) << 4));
      u32x4 h1  = *(const u32x4*)(rp + (((4 + u) ^ key) << 4));
      u32x4 l0_ = *(const u32x4*)(rp + ((8 | (u ^ key)) << 4));
      u32x4 l1_ = *(const u32x4*)(rp + ((8 | ((4 + u) ^ key)) << 4));
      f32x4 acc = {0.f, 0.f, 0.f, 0.f};
      acc = MFu(h0, Bh0, acc);
      acc = MFu(h0, Bl0, acc);
      acc = MFu(l0_, Bh0, acc);
      acc = MFu(h1, Bh1, acc);
      acc = MFu(h1, Bl1, acc);
      acc = MFu(l1_, Bh1, acc);
      float s0 = ((mw0 >> sh) & 1u) ? 0.f : acc.x;
      float s1 = ((mw1 >> sh) & 1u) ? 0.f : acc.y;
      float s2 = ((mw2 >> sh) & 1u) ? 0.f : acc.z;
      float s3 = ((mw3 >> sh) & 1u) ? 0.f : acc.w;
      rs += (s0 + s1) + (s2 + s3);
      H1 p0, p1;
      p0.h = pkrtz(s0, s1); p1.h = pkrtz(s2, s3);
      su[win][0] = p0.u; su[win][1] = p1.u;
    }
    // PV per window-pair (A k-slots: 4 cols of win-1, 4 cols of win)
    if (win & 1) {
      H8 aw;
      aw.u[0] = su[win - 1][0]; aw.u[1] = su[win - 1][1];
      aw.u[2] = su[win][0];     aw.u[3] = su[win][1];
      pv[0] = MF16(aw.v8, __builtin_bit_cast(f16x8, vbuf[0]), pv[0]);
      pv[1] = MF16(aw.v8, __builtin_bit_cast(f16x8, vbuf[1]), pv[1]);
      pv[2] = MF16(aw.v8, __builtin_bit_cast(f16x8, vbuf[2]), pv[2]);
      pv[3] = MF16(aw.v8, __builtin_bit_cast(f16x8, vbuf[3]), pv[3]);
    }
    __syncthreads();               // win+1 DMA drained; buffer free for win+2
  }

  // ---- row-sums -> red; S -> LDS transpose buffer (kbuf alias, 64 KB) ----
  rs += __shfl_xor(rs, 16);
  rs += __shfl_xor(rs, 32);
  if (l < 16) red[l][ks] = rs;
  {
    char* srow = &kbuf[0][0] + ln * 4096;
    const unsigned skey = (unsigned)ln << 3;
#pragma unroll
    for (int win = 0; win < NWIN; ++win) {
      unsigned Bo = 256u * win + 32u * ks + 8u * u;
      u32x2 pk2 = {su[win][0], su[win][1]};
      *(u32x2*)(srow + (Bo ^ skey)) = pk2;
    }
  }
  __syncthreads();
  if (tid < QT) {
    f32x4 r0 = *(const f32x4*)&red[tid][0];
    f32x4 r1 = *(const f32x4*)&red[tid][4];
    float s = ((r0.x + r0.y) + (r0.z + r0.w)) + ((r1.x + r1.y) + (r1.z + r1.w));
    dinv_s[tid] = 1.0f / fmaxf(s, 1e-14f);
  }
  __syncthreads();

  // ---- attn stores: 2 rows/wave, 1KB-contiguous nontemporal bursts ----
  {
    const char* Sb = &kbuf[0][0];
#pragma unroll
    for (int r = 0; r < 2; ++r) {
      const int rr = 2 * w + r;
      const float dv = dinv_s[rr];
      const char* sr = Sb + rr * 4096;
      const unsigned rk = (unsigned)rr << 3;
      float* arow = outA + (size_t)(b * Lq + q0 + rr) * Lq;
#pragma unroll
      for (int m = 0; m < 8; ++m) {
        u32x2 pk = *(const u32x2*)(sr + ((unsigned)(512 * m + 8 * l) ^ rk));
        H1 a0, a1; a0.u = pk.x; a1.u = pk.y;
        f32x4 st = {(float)a0.h.x * dv, (float)a0.h.y * dv,
                    (float)a1.h.x * dv, (float)a1.h.y * dv};
        __builtin_nontemporal_store(st, (f32x4*)(arow + 256 * m + 4 * l));
      }
    }
  }
  __syncthreads();                 // all Sb reads done -> Or may alias

  // ---- cross-ks O reduction (kbuf alias) + store ----
  {
    float (*Or)[16][66] = (float (*)[16][66])&kbuf[0][0];   // [8][16][66]
#pragma unroll
    for (int nt = 0; nt < 4; ++nt)
#pragma unroll
      for (int r2 = 0; r2 < 4; ++r2)
        Or[ks][4 * u + r2][16 * nt + ln] = pv[nt][r2];
    __syncthreads();
    {
      int q_ = tid >> 5, d = (tid & 31) * 2;
      float o0 = 0.f, o1 = 0.f;
#pragma unroll
      for (int k2 = 0; k2 < 8; ++k2) {
        o0 += Or[k2][q_][d];
        o1 += Or[k2][q_][d + 1];
      }
      float dvq = dinv_s[q_];
      f32x2 st = {o0 * dvq, o1 * dvq};
      *(f32x2*)(outO + (size_t)(b * Lq + q0 + q_) * Dd + d) = st;
    }
  }
}

extern "C" void kernel_launch(void* const* d_in, const int* in_sizes, int n_in,
                              void* d_out, int out_size, void* d_ws, size_t ws_size,
                              hipStream_t stream) {
  const float* q = (const float*)d_in[0];
  const float* k = (const float*)d_in[1];
  const float* v = (const float*)d_in[2];
  const int*   m = (const int*)d_in[3];
  float* outO = (float*)d_out;
  float* outA = outO + (size_t)Bb * Lq * Dd;

  char* ws = (char*)d_ws;
  u32x4* Kw4 = (u32x4*)ws;                    // 8 MB swizzled K h/l windows
  u32x4* Vq  = (u32x4*)(ws + (8u << 20));     // 4 MB V window-pair B-frags
  sdpa_prep<<<2048, 256, 0, stream>>>(k, v, Kw4, Vq);
  sdpa_main<<<Bb * (Lq / QT), NT, 0, stream>>>(q, (const char*)Kw4, Vq,
                                               (const i32x4*)m, outO, outA);
}